// Round 5
// baseline (318.126 us; speedup 1.0000x reference)
//
#include <hip/hip_runtime.h>

// ---------- types & helpers ----------
typedef short bf16x8 __attribute__((ext_vector_type(8)));   // 8 bf16 (4 VGPRs)
typedef float f32x4 __attribute__((ext_vector_type(4)));

__device__ __forceinline__ unsigned short f2bf(float f) {
  union { float f; unsigned u; } x; x.f = f;
  unsigned u = x.u;
  u += 0x7fffu + ((u >> 16) & 1u);      // round-to-nearest-even
  return (unsigned short)(u >> 16);
}

// ---------- 1. f32 -> bf16 conversion of all operands ----------
__global__ __launch_bounds__(256) void cvt_all(
    const float* __restrict__ text, const float* __restrict__ vis,
    const float* __restrict__ wq, const float* __restrict__ wk,
    const float* __restrict__ wv, const float* __restrict__ wo,
    unsigned short* __restrict__ o0, unsigned short* __restrict__ o1,
    unsigned short* __restrict__ o2, unsigned short* __restrict__ o3,
    unsigned short* __restrict__ o4, unsigned short* __restrict__ o5)
{
  long i4 = (long)blockIdx.x * 256 + threadIdx.x;   // index in float4 units
  const float* src; unsigned short* dst; long base;
  if      (i4 <   65536) { src = text; dst = o0; base = 0; }
  else if (i4 <  851968) { src = vis;  dst = o1; base = 65536; }
  else if (i4 < 1114112) { src = wq;   dst = o2; base = 851968; }
  else if (i4 < 1376256) { src = wk;   dst = o3; base = 1114112; }
  else if (i4 < 1638400) { src = wv;   dst = o4; base = 1376256; }
  else                   { src = wo;   dst = o5; base = 1638400; }
  long li = i4 - base;
  float4 f = reinterpret_cast<const float4*>(src)[li];
  uint2 u;
  u.x = (unsigned)f2bf(f.x) | ((unsigned)f2bf(f.y) << 16);
  u.y = (unsigned)f2bf(f.z) | ((unsigned)f2bf(f.w) << 16);
  reinterpret_cast<uint2*>(dst)[li] = u;
}

// ---------- 2a. generic bf16 GEMM  C[M,N] = A[M,K] @ B[N,K]^T (+bias), bf16 out ----------
__global__ __launch_bounds__(256) void gemm_abt_bf16(
    const unsigned short* __restrict__ A,
    const unsigned short* __restrict__ B,
    unsigned short* __restrict__ C,
    const float* __restrict__ bias,
    int K, int lda, int ldb, int ldc)
{
  __shared__ unsigned short As[64][40];   // +8 pad
  __shared__ unsigned short Bs[64][40];
  const int m0 = blockIdx.y * 64, n0 = blockIdx.x * 64;
  const int tid = threadIdx.x;
  const int lane = tid & 63, w = tid >> 6;
  const int wm = w >> 1, wn = w & 1;
  const int r16 = lane & 15, kg = lane >> 4;
  const int srow = tid >> 2, sseg = tid & 3;

  const f32x4 fzero = {0.f, 0.f, 0.f, 0.f};
  f32x4 acc[2][2];
#pragma unroll
  for (int i = 0; i < 2; ++i)
#pragma unroll
    for (int j = 0; j < 2; ++j) acc[i][j] = fzero;

  for (int k0 = 0; k0 < K; k0 += 32) {
    __syncthreads();
    *reinterpret_cast<int4*>(&As[srow][sseg * 8]) =
        *reinterpret_cast<const int4*>(&A[(long)(m0 + srow) * lda + k0 + sseg * 8]);
    *reinterpret_cast<int4*>(&Bs[srow][sseg * 8]) =
        *reinterpret_cast<const int4*>(&B[(long)(n0 + srow) * ldb + k0 + sseg * 8]);
    __syncthreads();
    bf16x8 a[2], b[2];
#pragma unroll
    for (int i = 0; i < 2; ++i)
      a[i] = *reinterpret_cast<const bf16x8*>(&As[wm * 32 + i * 16 + r16][kg * 8]);
#pragma unroll
    for (int j = 0; j < 2; ++j)
      b[j] = *reinterpret_cast<const bf16x8*>(&Bs[wn * 32 + j * 16 + r16][kg * 8]);
#pragma unroll
    for (int i = 0; i < 2; ++i)
#pragma unroll
      for (int j = 0; j < 2; ++j)
        acc[i][j] = __builtin_amdgcn_mfma_f32_16x16x32_bf16(a[i], b[j], acc[i][j], 0, 0, 0);
  }
#pragma unroll
  for (int i = 0; i < 2; ++i) {
#pragma unroll
    for (int j = 0; j < 2; ++j) {
      const int row = m0 + wm * 32 + i * 16 + kg * 4;
      const int col = n0 + wn * 32 + j * 16 + r16;
      const float bv = bias ? bias[col] : 0.f;
#pragma unroll
      for (int r = 0; r < 4; ++r)
        C[(long)(row + r) * ldc + col] = f2bf(acc[i][j][r] + bv);
    }
  }
}

// ---------- 2b. fused K/V projection: blockIdx.z selects (B,C,bias) ----------
__global__ __launch_bounds__(256) void gemm_abt_bf16_kv(
    const unsigned short* __restrict__ A,
    const unsigned short* __restrict__ B0,
    const unsigned short* __restrict__ B1,
    unsigned short* __restrict__ C0,
    unsigned short* __restrict__ C1,
    const float* __restrict__ bias0,
    const float* __restrict__ bias1,
    int K, int lda, int ldb, int ldc)
{
  const unsigned short* B = blockIdx.z ? B1 : B0;
  unsigned short* C = blockIdx.z ? C1 : C0;
  const float* bias = blockIdx.z ? bias1 : bias0;

  __shared__ unsigned short As[64][40];
  __shared__ unsigned short Bs[64][40];
  const int m0 = blockIdx.y * 64, n0 = blockIdx.x * 64;
  const int tid = threadIdx.x;
  const int lane = tid & 63, w = tid >> 6;
  const int wm = w >> 1, wn = w & 1;
  const int r16 = lane & 15, kg = lane >> 4;
  const int srow = tid >> 2, sseg = tid & 3;

  const f32x4 fzero = {0.f, 0.f, 0.f, 0.f};
  f32x4 acc[2][2];
#pragma unroll
  for (int i = 0; i < 2; ++i)
#pragma unroll
    for (int j = 0; j < 2; ++j) acc[i][j] = fzero;

  for (int k0 = 0; k0 < K; k0 += 32) {
    __syncthreads();
    *reinterpret_cast<int4*>(&As[srow][sseg * 8]) =
        *reinterpret_cast<const int4*>(&A[(long)(m0 + srow) * lda + k0 + sseg * 8]);
    *reinterpret_cast<int4*>(&Bs[srow][sseg * 8]) =
        *reinterpret_cast<const int4*>(&B[(long)(n0 + srow) * ldb + k0 + sseg * 8]);
    __syncthreads();
    bf16x8 a[2], b[2];
#pragma unroll
    for (int i = 0; i < 2; ++i)
      a[i] = *reinterpret_cast<const bf16x8*>(&As[wm * 32 + i * 16 + r16][kg * 8]);
#pragma unroll
    for (int j = 0; j < 2; ++j)
      b[j] = *reinterpret_cast<const bf16x8*>(&Bs[wn * 32 + j * 16 + r16][kg * 8]);
#pragma unroll
    for (int i = 0; i < 2; ++i)
#pragma unroll
      for (int j = 0; j < 2; ++j)
        acc[i][j] = __builtin_amdgcn_mfma_f32_16x16x32_bf16(a[i], b[j], acc[i][j], 0, 0, 0);
  }
#pragma unroll
  for (int i = 0; i < 2; ++i) {
#pragma unroll
    for (int j = 0; j < 2; ++j) {
      const int row = m0 + wm * 32 + i * 16 + kg * 4;
      const int col = n0 + wn * 32 + j * 16 + r16;
      const float bv = bias ? bias[col] : 0.f;
#pragma unroll
      for (int r = 0; r < 4; ++r)
        C[(long)(row + r) * ldc + col] = f2bf(acc[i][j][r] + bv);
    }
  }
}

// ---------- 3. scores + softmax over frames -> P[v][t][f*16+h] (bf16) ----------
__global__ __launch_bounds__(256) void scores_softmax(
    const unsigned short* __restrict__ Kp,   // [v*12][1024] = [v][f][h*64+d]
    const unsigned short* __restrict__ Qp,   // [256][1024]  = [t][h*64+d]
    unsigned short* __restrict__ P)          // [v][256][192]
{
  const int h = blockIdx.x, v = blockIdx.y;
  const int tid = threadIdx.x, lane = tid & 63, w = tid >> 6;
  const int r16 = lane & 15, kg = lane >> 4;
  __shared__ unsigned short Ks[16][72];
  __shared__ unsigned short Qs[256][72];

  if (tid < 96) {
    const int f = tid >> 3, seg = tid & 7;
    *reinterpret_cast<int4*>(&Ks[f][seg * 8]) =
        *reinterpret_cast<const int4*>(&Kp[(long)(v * 12 + f) * 1024 + h * 64 + seg * 8]);
  } else if (tid < 128) {   // zero-fill pad rows 12..15
    const int f = 12 + ((tid - 96) >> 3), seg = (tid - 96) & 7;
    int4 z; z.x = 0; z.y = 0; z.z = 0; z.w = 0;
    *reinterpret_cast<int4*>(&Ks[f][seg * 8]) = z;
  }
#pragma unroll
  for (int rep = 0; rep < 8; ++rep) {
    const int row = rep * 32 + (tid >> 3), seg = tid & 7;
    *reinterpret_cast<int4*>(&Qs[row][seg * 8]) =
        *reinterpret_cast<const int4*>(&Qp[(long)row * 1024 + h * 64 + seg * 8]);
  }
  __syncthreads();

  const f32x4 fzero = {0.f, 0.f, 0.f, 0.f};
  f32x4 acc[4];
#pragma unroll
  for (int j = 0; j < 4; ++j) acc[j] = fzero;

#pragma unroll
  for (int kk = 0; kk < 64; kk += 32) {
    bf16x8 a = *reinterpret_cast<const bf16x8*>(&Ks[r16][kk + kg * 8]);
#pragma unroll
    for (int j = 0; j < 4; ++j) {
      bf16x8 b = *reinterpret_cast<const bf16x8*>(&Qs[w * 64 + j * 16 + r16][kk + kg * 8]);
      acc[j] = __builtin_amdgcn_mfma_f32_16x16x32_bf16(a, b, acc[j], 0, 0, 0);
    }
  }
#pragma unroll
  for (int j = 0; j < 4; ++j) {
    float lm = -1e30f;
    if (kg < 3) {
#pragma unroll
      for (int r = 0; r < 4; ++r) lm = fmaxf(lm, acc[j][r] * 0.125f);
    }
    lm = fmaxf(lm, __shfl_xor(lm, 16));
    lm = fmaxf(lm, __shfl_xor(lm, 32));
    float p[4]; float ls = 0.f;
    if (kg < 3) {
#pragma unroll
      for (int r = 0; r < 4; ++r) { p[r] = __expf(acc[j][r] * 0.125f - lm); ls += p[r]; }
    }
    ls += __shfl_xor(ls, 16);
    ls += __shfl_xor(ls, 32);
    const float inv = 1.f / ls;
    if (kg < 3) {
      const int t = w * 64 + j * 16 + r16;
#pragma unroll
      for (int r = 0; r < 4; ++r)
        P[((long)v * 256 + t) * 192 + (kg * 4 + r) * 16 + h] = f2bf(p[r] * inv);
    }
  }
}

// ---------- 4a. Zh kernel: Z[vlocal][o][k=f*16+h] (bf16) for a v-chunk ----------
// Block (o-tile=64, v): phase-1 MFMA into swizzled LDS tile, then coalesced dump.
__global__ __launch_bounds__(256) void zh_kernel(
    const unsigned short* __restrict__ VPp,  // [v*12][1024] = [v][f][h*64+d]
    const unsigned short* __restrict__ Wo,   // [1024][1024] bf16
    unsigned short* __restrict__ Z,          // [vchunk][1024][192]
    int vbase, int vsh)                      // vchunk = 8 << vsh
{
  const int wgid = blockIdx.x;
  const int xcd = wgid & 7, idx = wgid >> 3;
  const int vlocal = ((idx & ((1 << vsh) - 1)) << 3) | xcd;
  const int v = vbase + vlocal;
  const int n0 = (idx >> vsh) << 6;

  const int tid = threadIdx.x, lane = tid & 63, w = tid >> 6;
  const int r16 = lane & 15, kg = lane >> 4;

  __shared__ unsigned short BsAll[64 * 192];   // [o][k] swizzled (16B slot ^ (o&7))

  const unsigned short* VPv = VPp + (long)v * 12 * 1024;
#pragma unroll
  for (int hi = 0; hi < 4; ++hi) {
    const int h = (w << 2) + hi;
    const int db = h * 64;
    f32x4 accp[4] = {{0.f,0.f,0.f,0.f},{0.f,0.f,0.f,0.f},{0.f,0.f,0.f,0.f},{0.f,0.f,0.f,0.f}};
#pragma unroll
    for (int kk = 0; kk < 64; kk += 32) {
      bf16x8 a = {0,0,0,0,0,0,0,0};
      if (r16 < 12)
        a = *reinterpret_cast<const bf16x8*>(&VPv[(long)r16 * 1024 + db + kk + kg * 8]);
      bf16x8 bfr[4];
#pragma unroll
      for (int j = 0; j < 4; ++j)
        bfr[j] = *reinterpret_cast<const bf16x8*>(
            &Wo[(long)(n0 + j * 16 + r16) * 1024 + db + kk + kg * 8]);
#pragma unroll
      for (int j = 0; j < 4; ++j)
        accp[j] = __builtin_amdgcn_mfma_f32_16x16x32_bf16(a, bfr[j], accp[j], 0, 0, 0);
    }
#pragma unroll
    for (int j = 0; j < 4; ++j) {
#pragma unroll
      for (int r = 0; r < 4; ++r) {
        const int f = kg * 4 + r;
        if (f < 12) {
          const int o = j * 16 + r16;
          const int k = f * 16 + h;
          BsAll[o * 192 + (((k >> 3) ^ (o & 7)) << 3) + (k & 7)] = f2bf(accp[j][r]);
        }
      }
    }
  }
  __syncthreads();
  // coalesced de-swizzled dump: 64 rows x 24 slots of 16B
  unsigned short* Zv = Z + ((long)vlocal * 1024 + n0) * 192;
  const int row = tid >> 2;
#pragma unroll
  for (int rep = 0; rep < 6; ++rep) {
    const int slot = (tid & 3) + (rep << 2);
    *reinterpret_cast<int4*>(&Zv[(long)row * 192 + slot * 8]) =
        *reinterpret_cast<const int4*>(&BsAll[row * 192 + ((slot ^ (row & 7)) << 3)]);
  }
}

// ---------- 4b. out GEMM: out[v][t][o] = P_v @ Z_v^T + bo (nt stores) ----------
__global__ __launch_bounds__(256) void out_gemm(
    const unsigned short* __restrict__ Z,    // [vchunk][1024][192]
    const unsigned short* __restrict__ P,    // [v][256][192]
    const float* __restrict__ bo,
    float* __restrict__ out,                 // [v][256][1024]
    int vbase, int vsh)
{
  const int wgid = blockIdx.x;
  const int xcd = wgid & 7, idx = wgid >> 3;
  const int vlocal = ((idx & ((1 << vsh) - 1)) << 3) | xcd;
  const int v = vbase + vlocal;
  const int n0 = (idx >> vsh) << 6;

  const int tid = threadIdx.x, lane = tid & 63, w = tid >> 6;
  const int r16 = lane & 15, kg = lane >> 4;

  __shared__ unsigned short Zs[64 * 192];    // swizzled, 24 KB

  // stage Z tile: one contiguous 24 KB region, coalesced; swizzle on LDS write
  const unsigned short* Zv = Z + ((long)vlocal * 1024 + n0) * 192;
  {
    const int row = tid >> 2;
#pragma unroll
    for (int rep = 0; rep < 6; ++rep) {
      const int slot = (tid & 3) + (rep << 2);
      *reinterpret_cast<int4*>(&Zs[row * 192 + ((slot ^ (row & 7)) << 3)]) =
          *reinterpret_cast<const int4*>(&Zv[(long)row * 192 + slot * 8]);
    }
  }
  // 2-deep rolling prefetch of P a-frags (issued before barrier; vmcnt covers)
  const unsigned short* Pv = P + (long)v * 256 * 192;
  bf16x8 aP[2][4];
#pragma unroll
  for (int s = 0; s < 2; ++s)
#pragma unroll
    for (int i = 0; i < 4; ++i)
      aP[s][i] = *reinterpret_cast<const bf16x8*>(
          &Pv[(long)(w * 64 + i * 16 + r16) * 192 + s * 32 + kg * 8]);

  __syncthreads();

  f32x4 acc[4][4];
#pragma unroll
  for (int i = 0; i < 4; ++i)
#pragma unroll
    for (int j = 0; j < 4; ++j) { f32x4 z = {0.f,0.f,0.f,0.f}; acc[i][j] = z; }

#pragma unroll
  for (int s = 0; s < 6; ++s) {
    const int k0 = s * 32;
    bf16x8 b[4];
#pragma unroll
    for (int j = 0; j < 4; ++j) {
      const int row = j * 16 + r16;
      const int slot = (k0 >> 3) + kg;
      b[j] = *reinterpret_cast<const bf16x8*>(
          &Zs[row * 192 + ((slot ^ (row & 7)) << 3)]);
    }
    bf16x8 aC[4];
#pragma unroll
    for (int i = 0; i < 4; ++i) aC[i] = aP[s & 1][i];
    if (s < 4) {
#pragma unroll
      for (int i = 0; i < 4; ++i)
        aP[s & 1][i] = *reinterpret_cast<const bf16x8*>(
            &Pv[(long)(w * 64 + i * 16 + r16) * 192 + (k0 + 64) + kg * 8]);
    }
#pragma unroll
    for (int i = 0; i < 4; ++i)
#pragma unroll
      for (int j = 0; j < 4; ++j)
        acc[i][j] = __builtin_amdgcn_mfma_f32_16x16x32_bf16(aC[i], b[j], acc[i][j], 0, 0, 0);
  }
#pragma unroll
  for (int i = 0; i < 4; ++i) {
#pragma unroll
    for (int j = 0; j < 4; ++j) {
      const int trow = w * 64 + i * 16 + kg * 4;
      const int col = n0 + j * 16 + r16;
      const float bv = bo[col];
#pragma unroll
      for (int r = 0; r < 4; ++r)
        __builtin_nontemporal_store(acc[i][j][r] + bv,
            &out[((long)v * 256 + trow + r) * 1024 + col]);
    }
  }
}

// ---------- launch ----------
extern "C" void kernel_launch(void* const* d_in, const int* in_sizes, int n_in,
                              void* d_out, int out_size, void* d_ws, size_t ws_size,
                              hipStream_t stream) {
  const float* text = (const float*)d_in[0];
  const float* vis  = (const float*)d_in[1];
  const float* wq   = (const float*)d_in[2];
  const float* bq   = (const float*)d_in[3];
  const float* wk   = (const float*)d_in[4];
  const float* bk   = (const float*)d_in[5];
  const float* wv   = (const float*)d_in[6];
  const float* bv   = (const float*)d_in[7];
  const float* wo   = (const float*)d_in[8];
  const float* bo   = (const float*)d_in[9];
  float* out = (float*)d_out;

  unsigned short* text16 = (unsigned short*)d_ws;      // 262144
  unsigned short* vis16  = text16 + 262144;            // 3145728
  unsigned short* wq16   = vis16  + 3145728;           // 1048576
  unsigned short* wk16   = wq16   + 1048576;           // 1048576
  unsigned short* wv16   = wk16   + 1048576;           // 1048576
  unsigned short* wo16   = wv16   + 1048576;           // 1048576
  unsigned short* q16    = wo16   + 1048576;           // 262144
  unsigned short* k16    = q16    + 262144;            // 3145728
  unsigned short* vp16   = k16    + 3145728;           // 3145728
  unsigned short* P      = vp16   + 3145728;           // 12582912
  unsigned short* Zbuf   = P     + 12582912;           // up to 50331648 (ws-adaptive)
  const size_t base_shorts = 26738688;                 // everything before Zbuf

  // choose largest power-of-2 v-chunk whose Z slab fits the workspace
  size_t avail_shorts = (ws_size / 2 > base_shorts) ? (ws_size / 2 - base_shorts) : 0;
  int vchunk = 256;
  while (vchunk > 8 && (size_t)vchunk * 1024 * 192 > avail_shorts) vchunk >>= 1;
  int vsh = 0; { int t = vchunk >> 3; while (t > 1) { t >>= 1; ++vsh; } }

  cvt_all<<<7424, 256, 0, stream>>>(text, vis, wq, wk, wv, wo,
                                    text16, vis16, wq16, wk16, wv16, wo16);
  gemm_abt_bf16<<<dim3(16, 4), 256, 0, stream>>>(text16, wq16, q16, bq, 1024, 1024, 1024, 1024);
  gemm_abt_bf16_kv<<<dim3(16, 48, 2), 256, 0, stream>>>(
      vis16, wk16, wv16, k16, vp16, bk, bv, 1024, 1024, 1024, 1024);
  scores_softmax<<<dim3(16, 256), 256, 0, stream>>>(k16, q16, P);
  for (int vb = 0; vb < 256; vb += vchunk) {
    zh_kernel<<<16 * vchunk, 256, 0, stream>>>(vp16, wo16, Zbuf, vb, vsh);
    out_gemm<<<16 * vchunk, 256, 0, stream>>>(Zbuf, P, bo, out, vb, vsh);
  }
}

// Round 7
// 231.076 us; speedup vs baseline: 1.3767x; 1.3767x over previous
//
#include <hip/hip_runtime.h>

// ---------- types & helpers ----------
typedef short bf16x8 __attribute__((ext_vector_type(8)));   // 8 bf16 (4 VGPRs)
typedef float f32x4 __attribute__((ext_vector_type(4)));

__device__ __forceinline__ unsigned short f2bf(float f) {
  union { float f; unsigned u; } x; x.f = f;
  unsigned u = x.u;
  u += 0x7fffu + ((u >> 16) & 1u);      // round-to-nearest-even
  return (unsigned short)(u >> 16);
}

// ---------- 1. f32 -> bf16 conversion of all operands ----------
__global__ __launch_bounds__(256) void cvt_all(
    const float* __restrict__ text, const float* __restrict__ vis,
    const float* __restrict__ wq, const float* __restrict__ wk,
    const float* __restrict__ wv, const float* __restrict__ wo,
    unsigned short* __restrict__ o0, unsigned short* __restrict__ o1,
    unsigned short* __restrict__ o2, unsigned short* __restrict__ o3,
    unsigned short* __restrict__ o4, unsigned short* __restrict__ o5)
{
  long i4 = (long)blockIdx.x * 256 + threadIdx.x;   // index in float4 units
  const float* src; unsigned short* dst; long base;
  if      (i4 <   65536) { src = text; dst = o0; base = 0; }
  else if (i4 <  851968) { src = vis;  dst = o1; base = 65536; }
  else if (i4 < 1114112) { src = wq;   dst = o2; base = 851968; }
  else if (i4 < 1376256) { src = wk;   dst = o3; base = 1114112; }
  else if (i4 < 1638400) { src = wv;   dst = o4; base = 1376256; }
  else                   { src = wo;   dst = o5; base = 1638400; }
  long li = i4 - base;
  float4 f = reinterpret_cast<const float4*>(src)[li];
  uint2 u;
  u.x = (unsigned)f2bf(f.x) | ((unsigned)f2bf(f.y) << 16);
  u.y = (unsigned)f2bf(f.z) | ((unsigned)f2bf(f.w) << 16);
  reinterpret_cast<uint2*>(dst)[li] = u;
}

// ---------- 2a. generic bf16 GEMM  C[M,N] = A[M,K] @ B[N,K]^T (+bias), bf16 out ----------
__global__ __launch_bounds__(256) void gemm_abt_bf16(
    const unsigned short* __restrict__ A,
    const unsigned short* __restrict__ B,
    unsigned short* __restrict__ C,
    const float* __restrict__ bias,
    int K, int lda, int ldb, int ldc)
{
  __shared__ unsigned short As[64][40];   // +8 pad
  __shared__ unsigned short Bs[64][40];
  const int m0 = blockIdx.y * 64, n0 = blockIdx.x * 64;
  const int tid = threadIdx.x;
  const int lane = tid & 63, w = tid >> 6;
  const int wm = w >> 1, wn = w & 1;
  const int r16 = lane & 15, kg = lane >> 4;
  const int srow = tid >> 2, sseg = tid & 3;

  const f32x4 fzero = {0.f, 0.f, 0.f, 0.f};
  f32x4 acc[2][2];
#pragma unroll
  for (int i = 0; i < 2; ++i)
#pragma unroll
    for (int j = 0; j < 2; ++j) acc[i][j] = fzero;

  for (int k0 = 0; k0 < K; k0 += 32) {
    __syncthreads();
    *reinterpret_cast<int4*>(&As[srow][sseg * 8]) =
        *reinterpret_cast<const int4*>(&A[(long)(m0 + srow) * lda + k0 + sseg * 8]);
    *reinterpret_cast<int4*>(&Bs[srow][sseg * 8]) =
        *reinterpret_cast<const int4*>(&B[(long)(n0 + srow) * ldb + k0 + sseg * 8]);
    __syncthreads();
    bf16x8 a[2], b[2];
#pragma unroll
    for (int i = 0; i < 2; ++i)
      a[i] = *reinterpret_cast<const bf16x8*>(&As[wm * 32 + i * 16 + r16][kg * 8]);
#pragma unroll
    for (int j = 0; j < 2; ++j)
      b[j] = *reinterpret_cast<const bf16x8*>(&Bs[wn * 32 + j * 16 + r16][kg * 8]);
#pragma unroll
    for (int i = 0; i < 2; ++i)
#pragma unroll
      for (int j = 0; j < 2; ++j)
        acc[i][j] = __builtin_amdgcn_mfma_f32_16x16x32_bf16(a[i], b[j], acc[i][j], 0, 0, 0);
  }
#pragma unroll
  for (int i = 0; i < 2; ++i) {
#pragma unroll
    for (int j = 0; j < 2; ++j) {
      const int row = m0 + wm * 32 + i * 16 + kg * 4;
      const int col = n0 + wn * 32 + j * 16 + r16;
      const float bv = bias ? bias[col] : 0.f;
#pragma unroll
      for (int r = 0; r < 4; ++r)
        C[(long)(row + r) * ldc + col] = f2bf(acc[i][j][r] + bv);
    }
  }
}

// ---------- 2b. fused K/V projection: blockIdx.z selects (B,C,bias) ----------
__global__ __launch_bounds__(256) void gemm_abt_bf16_kv(
    const unsigned short* __restrict__ A,
    const unsigned short* __restrict__ B0,
    const unsigned short* __restrict__ B1,
    unsigned short* __restrict__ C0,
    unsigned short* __restrict__ C1,
    const float* __restrict__ bias0,
    const float* __restrict__ bias1,
    int K, int lda, int ldb, int ldc)
{
  const unsigned short* B = blockIdx.z ? B1 : B0;
  unsigned short* C = blockIdx.z ? C1 : C0;
  const float* bias = blockIdx.z ? bias1 : bias0;

  __shared__ unsigned short As[64][40];
  __shared__ unsigned short Bs[64][40];
  const int m0 = blockIdx.y * 64, n0 = blockIdx.x * 64;
  const int tid = threadIdx.x;
  const int lane = tid & 63, w = tid >> 6;
  const int wm = w >> 1, wn = w & 1;
  const int r16 = lane & 15, kg = lane >> 4;
  const int srow = tid >> 2, sseg = tid & 3;

  const f32x4 fzero = {0.f, 0.f, 0.f, 0.f};
  f32x4 acc[2][2];
#pragma unroll
  for (int i = 0; i < 2; ++i)
#pragma unroll
    for (int j = 0; j < 2; ++j) acc[i][j] = fzero;

  for (int k0 = 0; k0 < K; k0 += 32) {
    __syncthreads();
    *reinterpret_cast<int4*>(&As[srow][sseg * 8]) =
        *reinterpret_cast<const int4*>(&A[(long)(m0 + srow) * lda + k0 + sseg * 8]);
    *reinterpret_cast<int4*>(&Bs[srow][sseg * 8]) =
        *reinterpret_cast<const int4*>(&B[(long)(n0 + srow) * ldb + k0 + sseg * 8]);
    __syncthreads();
    bf16x8 a[2], b[2];
#pragma unroll
    for (int i = 0; i < 2; ++i)
      a[i] = *reinterpret_cast<const bf16x8*>(&As[wm * 32 + i * 16 + r16][kg * 8]);
#pragma unroll
    for (int j = 0; j < 2; ++j)
      b[j] = *reinterpret_cast<const bf16x8*>(&Bs[wn * 32 + j * 16 + r16][kg * 8]);
#pragma unroll
    for (int i = 0; i < 2; ++i)
#pragma unroll
      for (int j = 0; j < 2; ++j)
        acc[i][j] = __builtin_amdgcn_mfma_f32_16x16x32_bf16(a[i], b[j], acc[i][j], 0, 0, 0);
  }
#pragma unroll
  for (int i = 0; i < 2; ++i) {
#pragma unroll
    for (int j = 0; j < 2; ++j) {
      const int row = m0 + wm * 32 + i * 16 + kg * 4;
      const int col = n0 + wn * 32 + j * 16 + r16;
      const float bv = bias ? bias[col] : 0.f;
#pragma unroll
      for (int r = 0; r < 4; ++r)
        C[(long)(row + r) * ldc + col] = f2bf(acc[i][j][r] + bv);
    }
  }
}

// ---------- 3. scores + softmax over frames -> P[v][t][k = h*12+f] (bf16) ----------
__global__ __launch_bounds__(256) void scores_softmax(
    const unsigned short* __restrict__ Kp,   // [v*12][1024] = [v][f][h*64+d]
    const unsigned short* __restrict__ Qp,   // [256][1024]  = [t][h*64+d]
    unsigned short* __restrict__ P)          // [v][256][192], k = h*12+f
{
  const int h = blockIdx.x, v = blockIdx.y;
  const int tid = threadIdx.x, lane = tid & 63, w = tid >> 6;
  const int r16 = lane & 15, kg = lane >> 4;
  __shared__ unsigned short Ks[16][72];
  __shared__ unsigned short Qs[256][72];

  if (tid < 96) {
    const int f = tid >> 3, seg = tid & 7;
    *reinterpret_cast<int4*>(&Ks[f][seg * 8]) =
        *reinterpret_cast<const int4*>(&Kp[(long)(v * 12 + f) * 1024 + h * 64 + seg * 8]);
  } else if (tid < 128) {   // zero-fill pad rows 12..15
    const int f = 12 + ((tid - 96) >> 3), seg = (tid - 96) & 7;
    int4 z; z.x = 0; z.y = 0; z.z = 0; z.w = 0;
    *reinterpret_cast<int4*>(&Ks[f][seg * 8]) = z;
  }
#pragma unroll
  for (int rep = 0; rep < 8; ++rep) {
    const int row = rep * 32 + (tid >> 3), seg = tid & 7;
    *reinterpret_cast<int4*>(&Qs[row][seg * 8]) =
        *reinterpret_cast<const int4*>(&Qp[(long)row * 1024 + h * 64 + seg * 8]);
  }
  __syncthreads();

  const f32x4 fzero = {0.f, 0.f, 0.f, 0.f};
  f32x4 acc[4];
#pragma unroll
  for (int j = 0; j < 4; ++j) acc[j] = fzero;

#pragma unroll
  for (int kk = 0; kk < 64; kk += 32) {
    bf16x8 a = *reinterpret_cast<const bf16x8*>(&Ks[r16][kk + kg * 8]);
#pragma unroll
    for (int j = 0; j < 4; ++j) {
      bf16x8 b = *reinterpret_cast<const bf16x8*>(&Qs[w * 64 + j * 16 + r16][kk + kg * 8]);
      acc[j] = __builtin_amdgcn_mfma_f32_16x16x32_bf16(a, b, acc[j], 0, 0, 0);
    }
  }
#pragma unroll
  for (int j = 0; j < 4; ++j) {
    float lm = -1e30f;
    if (kg < 3) {
#pragma unroll
      for (int r = 0; r < 4; ++r) lm = fmaxf(lm, acc[j][r] * 0.125f);
    }
    lm = fmaxf(lm, __shfl_xor(lm, 16));
    lm = fmaxf(lm, __shfl_xor(lm, 32));
    float p[4]; float ls = 0.f;
    if (kg < 3) {
#pragma unroll
      for (int r = 0; r < 4; ++r) { p[r] = __expf(acc[j][r] * 0.125f - lm); ls += p[r]; }
    }
    ls += __shfl_xor(ls, 16);
    ls += __shfl_xor(ls, 32);
    const float inv = 1.f / ls;
    if (kg < 3) {
      const int t = w * 64 + j * 16 + r16;
      uint2 u2;
      u2.x = (unsigned)f2bf(p[0] * inv) | ((unsigned)f2bf(p[1] * inv) << 16);
      u2.y = (unsigned)f2bf(p[2] * inv) | ((unsigned)f2bf(p[3] * inv) << 16);
      // k = h*12 + (kg*4 + r): 4 consecutive shorts -> one 8B store
      *reinterpret_cast<uint2*>(&P[((long)v * 256 + t) * 192 + h * 12 + kg * 4]) = u2;
    }
  }
}

// ---------- 4. fused Zh + combine ----------
// Phase 1 (barrier-free): Zh fragments read directly from global (L2/L3-resident),
// results -> BsAll[64 o][192 k] swizzled LDS, k = h*12+f.
// Phase 2: one barrier; P a-frags from global (2-deep rolling prefetch), b from LDS.
// Epilogue: BsAll reused as per-wave f32 transpose buffer -> f32x4 nt stores
// (4 x 256B contiguous segments per store instruction).
__global__ __launch_bounds__(256) void combine(
    const unsigned short* __restrict__ VPp,  // [v*12][1024] = [v][f][h*64+d]
    const unsigned short* __restrict__ Wo,   // [1024][1024] bf16
    const unsigned short* __restrict__ P,    // [v][256][192], k = h*12+f
    const float* __restrict__ bo,
    float* __restrict__ out)                 // [v][256][1024]
{
  // XCD-aware bijective swizzle: 4096 = 8 xcd * 32 vgrp * 16 otile
  const int wgid = blockIdx.x;
  const int xcd = wgid & 7, idx = wgid >> 3;
  const int v = ((idx & 31) << 3) | xcd;
  const int n0 = (idx >> 5) << 6;

  const int tid = threadIdx.x, lane = tid & 63, w = tid >> 6;
  const int r16 = lane & 15, kg = lane >> 4;

  __shared__ unsigned short BsAll[64 * 192];   // 24 KB; reused as f32 scratch in epilogue

  // ---- phase 1: Zh slice, no barriers ----
  const unsigned short* VPv = VPp + (long)v * 12 * 1024;
#pragma unroll
  for (int hi = 0; hi < 4; ++hi) {
    const int h = (w << 2) + hi;
    const int db = h * 64;
    f32x4 accp[4] = {{0.f,0.f,0.f,0.f},{0.f,0.f,0.f,0.f},{0.f,0.f,0.f,0.f},{0.f,0.f,0.f,0.f}};
#pragma unroll
    for (int kk = 0; kk < 64; kk += 32) {
      bf16x8 a = {0,0,0,0,0,0,0,0};
      if (r16 < 12)
        a = *reinterpret_cast<const bf16x8*>(&VPv[(long)r16 * 1024 + db + kk + kg * 8]);
      bf16x8 bfr[4];
#pragma unroll
      for (int j = 0; j < 4; ++j)
        bfr[j] = *reinterpret_cast<const bf16x8*>(
            &Wo[(long)(n0 + j * 16 + r16) * 1024 + db + kk + kg * 8]);
#pragma unroll
      for (int j = 0; j < 4; ++j)
        accp[j] = __builtin_amdgcn_mfma_f32_16x16x32_bf16(a, bfr[j], accp[j], 0, 0, 0);
    }
#pragma unroll
    for (int j = 0; j < 4; ++j) {
#pragma unroll
      for (int r = 0; r < 4; ++r) {
        const int f = kg * 4 + r;
        if (f < 12) {
          const int o = j * 16 + r16;
          const int k = h * 12 + f;     // matches P's k-labeling
          BsAll[o * 192 + (((k >> 3) ^ (o & 7)) << 3) + (k & 7)] = f2bf(accp[j][r]);
        }
      }
    }
  }

  // prefetch first two phase-2 a-frag sets while phase-1 tail drains
  const unsigned short* Pv = P + (long)v * 256 * 192;
  bf16x8 aP[2][4];
#pragma unroll
  for (int s = 0; s < 2; ++s)
#pragma unroll
    for (int i = 0; i < 4; ++i)
      aP[s][i] = *reinterpret_cast<const bf16x8*>(
          &Pv[(long)(w * 64 + i * 16 + r16) * 192 + s * 32 + kg * 8]);

  __syncthreads();

  // ---- phase 2: out tile = P_v @ BsAll^T ----
  f32x4 acc[4][4];
#pragma unroll
  for (int i = 0; i < 4; ++i)
#pragma unroll
    for (int j = 0; j < 4; ++j) { f32x4 z = {0.f,0.f,0.f,0.f}; acc[i][j] = z; }

#pragma unroll
  for (int s = 0; s < 6; ++s) {
    const int k0 = s * 32;
    bf16x8 b[4];
#pragma unroll
    for (int j = 0; j < 4; ++j) {
      const int row = j * 16 + r16;
      const int slot = (k0 >> 3) + kg;
      b[j] = *reinterpret_cast<const bf16x8*>(
          &BsAll[row * 192 + ((slot ^ (row & 7)) << 3)]);
    }
    bf16x8 aC[4];
#pragma unroll
    for (int i = 0; i < 4; ++i) aC[i] = aP[s & 1][i];
    if (s < 4) {
#pragma unroll
      for (int i = 0; i < 4; ++i)
        aP[s & 1][i] = *reinterpret_cast<const bf16x8*>(
            &Pv[(long)(w * 64 + i * 16 + r16) * 192 + (k0 + 64) + kg * 8]);
    }
#pragma unroll
    for (int i = 0; i < 4; ++i)
#pragma unroll
      for (int j = 0; j < 4; ++j)
        acc[i][j] = __builtin_amdgcn_mfma_f32_16x16x32_bf16(aC[i], b[j], acc[i][j], 0, 0, 0);
  }

  // ---- epilogue: per-wave LDS transpose -> coalesced f32x4 nt stores ----
  __syncthreads();                           // BsAll dead; reuse as scratch
  float* Eps = reinterpret_cast<float*>(BsAll);
  const int c4 = lane & 15;                  // f32x4 column (16 cols of 4)
  const int rr = lane >> 4;                  // row sub-group
  f32x4 bias4 = *reinterpret_cast<const f32x4*>(&bo[n0 + c4 * 4]);
  const int wbase = w * 1088;                // per-wave region: 16 rows x 68 f32

#pragma unroll
  for (int i = 0; i < 4; ++i) {
#pragma unroll
    for (int j = 0; j < 4; ++j)
#pragma unroll
      for (int r = 0; r < 4; ++r)
        Eps[wbase + (kg * 4 + r) * 68 + j * 16 + r16] = acc[i][j][r];
    asm volatile("s_waitcnt lgkmcnt(0)" ::: "memory");   // wave-internal transpose fence
#pragma unroll
    for (int q = 0; q < 4; ++q) {
      const int row16 = rr + q * 4;
      f32x4 vle = *reinterpret_cast<const f32x4*>(&Eps[wbase + row16 * 68 + c4 * 4]);
      vle += bias4;
      f32x4* dst = reinterpret_cast<f32x4*>(
          &out[((long)v * 256 + w * 64 + i * 16 + row16) * 1024 + n0 + c4 * 4]);
      __builtin_nontemporal_store(vle, dst);
    }
    asm volatile("s_waitcnt lgkmcnt(0)" ::: "memory");   // reads done before next overwrite
  }
}

// ---------- launch ----------
extern "C" void kernel_launch(void* const* d_in, const int* in_sizes, int n_in,
                              void* d_out, int out_size, void* d_ws, size_t ws_size,
                              hipStream_t stream) {
  const float* text = (const float*)d_in[0];
  const float* vis  = (const float*)d_in[1];
  const float* wq   = (const float*)d_in[2];
  const float* bq   = (const float*)d_in[3];
  const float* wk   = (const float*)d_in[4];
  const float* bk   = (const float*)d_in[5];
  const float* wv   = (const float*)d_in[6];
  const float* bv   = (const float*)d_in[7];
  const float* wo   = (const float*)d_in[8];
  const float* bo   = (const float*)d_in[9];
  float* out = (float*)d_out;

  unsigned short* text16 = (unsigned short*)d_ws;      // 262144
  unsigned short* vis16  = text16 + 262144;            // 3145728
  unsigned short* wq16   = vis16  + 3145728;           // 1048576
  unsigned short* wk16   = wq16   + 1048576;           // 1048576
  unsigned short* wv16   = wk16   + 1048576;           // 1048576
  unsigned short* wo16   = wv16   + 1048576;           // 1048576
  unsigned short* q16    = wo16   + 1048576;           // 262144
  unsigned short* k16    = q16    + 262144;            // 3145728
  unsigned short* vp16   = k16    + 3145728;           // 3145728
  unsigned short* P      = vp16   + 3145728;           // 12582912  (total ~51 MB)

  cvt_all<<<7424, 256, 0, stream>>>(text, vis, wq, wk, wv, wo,
                                    text16, vis16, wq16, wk16, wv16, wo16);
  gemm_abt_bf16<<<dim3(16, 4), 256, 0, stream>>>(text16, wq16, q16, bq, 1024, 1024, 1024, 1024);
  gemm_abt_bf16_kv<<<dim3(16, 48, 2), 256, 0, stream>>>(
      vis16, wk16, wv16, k16, vp16, bk, bv, 1024, 1024, 1024, 1024);
  scores_softmax<<<dim3(16, 256), 256, 0, stream>>>(k16, q16, P);
  combine<<<4096, 256, 0, stream>>>(vp16, wo16, P, bo, out);
}